// Round 2
// baseline (320.063 us; speedup 1.0000x reference)
//
#include <hip/hip_runtime.h>

typedef unsigned int uint;
typedef __bf16 bf16_t;
typedef bf16_t bf16x8 __attribute__((ext_vector_type(8)));
typedef float floatx4 __attribute__((ext_vector_type(4)));

struct __align__(8) us4 { unsigned short x, y, z, w; };

__device__ __forceinline__ unsigned short f2b(float f) {
    unsigned u = __float_as_uint(f);
    u = u + 0x7FFFu + ((u >> 16) & 1u);   // RNE
    return (unsigned short)(u >> 16);
}
__device__ __forceinline__ float b2f(unsigned short h) {
    return __uint_as_float(((unsigned)h) << 16);
}

// async global->LDS, 16B per lane; LDS dest is wave-uniform base + lane*16
__device__ __forceinline__ void g2l16(const void* g, void* l) {
    __builtin_amdgcn_global_load_lds((__attribute__((address_space(1))) void*)g,
                                     (__attribute__((address_space(3))) void*)l,
                                     16, 0, 0);
}

// ---------------------------------------------------------------------------
// gemm256: O[m,n] = sum_k A[m,k]*B[n,k], row stride LD (template). 256x256
// tile, BK=64, 512 threads = 8 waves (2M x 4N), per-wave 128x64 (acc[8][4]).
//
// Phase-split schedule (T3+T4+T5, derived from the m201 template):
//   2 LDS buffers x 4 half-slots {A_k0, A_k1, B_k0, B_k1}, 16KB each (128KB).
//   Per K-tile t (buffer t&1), 4 phases (k-half x j-pair quadrants):
//     q0: read A_k0 frags (8) + B_k0 j01 (2) | stage A_k1(t+1) | bar | 16 MFMA | bar
//     q1: read B_k0 j23 (2)                  | stage B_k1(t+1) | vmcnt(8) bar | 16 MFMA | bar
//     q2: read A_k1 frags (8) + B_k1 j01 (2) | stage A_k0(t+2) | bar | 16 MFMA | bar
//     q3: read B_k1 j23 (2)                  | stage B_k0(t+2) | vmcnt(8) bar | 16 MFMA | bar
//   vmcnt is placed ONE BARRIER BEFORE the dependent reads (a wave's vmcnt
//   only covers its own loads; the barrier publishes the guarantee to all
//   waves). Counted (8 = 4 halves x 2 loads in flight), never 0 in steady
//   state. Every stage targets a slot whose last ds_read is >=2 barriers old.
//   Stage lead = 5-6 phases ~ full HBM latency.
//
// LDS slot layout: 256 rows x 64B (32 k-elems). 16B-chunk swizzle:
//   chunk' = chunk ^ ((row>>1)&3)  -> exact 2-way bank aliasing (free).
//   Staging keeps the linear global_load_lds dest; the SOURCE address is
//   pre-swizzled with the same involution (both-sides rule).
//
// Grid (MODE != 6): 1-D, XCD swizzle id&7, g=id>>3, nt=g%NTN, ms=(g/NTN)*8+xcd.
// BMS: ms decodes (batch = ms&7, mtile = ms>>3) -> batch pinned to XCD.
// MODE 0: bf16 store
// MODE 3: f32 store of acc + R (residual)
// MODE 5: bf16 store of acc*(scale/Sn[row]) + R   (attn: fused q-softmax)
// MODE 4: fused qkv, B=concat(Wq,Wk,Wv)[1536x512]:
//   n0<512    : store exp(acc) -> O (=eq), atomicAdd row sums into Sq[m]
//   512..1023 : store exp(acc) transposed -> O2 (=ekT[b,d,n]), atomicAdd
//               column sums into Sk[b*512+d]
//   >=1024    : store acc transposed -> O3 (=vT[b,e,n])
// MODE 6: ctx split-K partial: grid 256 = (b 0..7) x (sk 0..7) x (mt,ntc 2x2),
//   A=vT[b, mt*256.., sk*512..], B=kT[b, ntc*256.., sk*512..], f32 store of
//   the 256x256 partial into P[(b*32 + sk*4 + mt*2 + ntc)*65536 + r*256 + c].
// ---------------------------------------------------------------------------
template <int MODE, int NTN, bool BMS, int LD>
__global__ __launch_bounds__(512, 2) void gemm256(
    const unsigned short* __restrict__ A, const unsigned short* __restrict__ B,
    void* __restrict__ O, const unsigned short* __restrict__ R,
    unsigned short* __restrict__ O2, unsigned short* __restrict__ O3,
    float* __restrict__ Sq, float* __restrict__ Sk,
    const float* __restrict__ Sn,
    int K, long long sB, float scale)
{
    __shared__ __attribute__((aligned(16))) unsigned short Ls[2][4][8192]; // 128 KB

    const uint id = blockIdx.x;
    const int tid = threadIdx.x;
    const int l = tid & 63;
    const int w = tid >> 6;
    const int wr = w >> 2;            // 0..1 : 128-row half of C
    const int wc = w & 3;             // 0..3 : 64-col strip of C

    int arow0 = 0, n0 = 0, bb = 0;
    const unsigned short* Ab;
    const unsigned short* Bbp;
    long long pbase = 0;

    if constexpr (MODE == 6) {
        const int mt = (int)(id >> 1) & 1, ntc = (int)id & 1;
        const int zz = (int)(id >> 2);
        const int b6 = zz & 7, sk6 = zz >> 3;
        Ab  = A + ((long long)b6 * 512 + mt  * 256) * 4096 + sk6 * 512;
        Bbp = B + ((long long)b6 * 512 + ntc * 256) * 4096 + sk6 * 512;
        pbase = (long long)(b6 * 32 + sk6 * 4 + mt * 2 + ntc) * 65536;
    } else {
        const uint xcd = id & 7;
        const uint g = id >> 3;
        const uint nt = g % NTN;
        const uint mg = g / NTN;
        const uint ms = mg * 8 + xcd;
        if constexpr (BMS) { bb = (int)(ms & 7); arow0 = bb * 4096 + (int)(ms >> 3) * 256; }
        else               { bb = 0;             arow0 = (int)ms * 256; }
        n0 = (int)nt * 256;
        Ab  = A + (long long)arow0 * LD;
        Bbp = B + (long long)bb * sB + (long long)n0 * LD;
    }

    // ---- staging source pointers (pre-swizzled). Thread covers LDS 16B
    // chunks n0i (call 0) and n0i+64 (call 1) of each slot; chunk n holds
    // source chunk lc = (n&3) ^ ((n>>3)&3) of row n>>2.
    const int n0i = w * 128 + l;
    const int n1i = n0i + 64;
    const unsigned short* pA0 = Ab  + (long long)(n0i >> 2) * LD + ((n0i & 3) ^ ((n0i >> 3) & 3)) * 8;
    const unsigned short* pA1 = Ab  + (long long)(n1i >> 2) * LD + ((n1i & 3) ^ ((n1i >> 3) & 3)) * 8;
    const unsigned short* pB0 = Bbp + (long long)(n0i >> 2) * LD + ((n0i & 3) ^ ((n0i >> 3) & 3)) * 8;
    const unsigned short* pB1 = Bbp + (long long)(n1i >> 2) * LD + ((n1i & 3) ^ ((n1i >> 3) & 3)) * 8;

#define STG(bufi, sl, p0, p1, koff) do {                                    \
        unsigned short* d_ = &Ls[bufi][sl][0] + n0i * 8;                    \
        g2l16((p0) + (koff), d_);                                           \
        g2l16((p1) + (koff), d_ + 512);                                     \
    } while (0)

    // ---- ds_read fragment addressing (byte offsets within a slot)
    const int fr = l & 15;
    const int c0 = l >> 4;
    const int swz = (c0 ^ ((fr >> 1) & 3)) << 4;
    const int aoff = (wr * 128 + fr) * 64 + swz;   // + i*1024
    const int boff = (wc * 64 + fr) * 64 + swz;    // + j*1024

    floatx4 acc[8][4] = {};
    const int NTk = K >> 6;                        // 512 -> 8 K-tiles

    // prologue: A_k0(0), B_k0(0), A_k1(0), B_k1(0), A_k0(1), B_k0(1)
    STG(0, 0, pA0, pA1, 0);
    STG(0, 2, pB0, pB1, 0);
    STG(0, 1, pA0, pA1, 32);
    STG(0, 3, pB0, pB1, 32);
    if (NTk > 1) {
        STG(1, 0, pA0, pA1, 64);
        STG(1, 2, pB0, pB1, 64);
    }
    asm volatile("s_waitcnt vmcnt(8)" ::: "memory");   // A_k0(0), B_k0(0) landed
    __builtin_amdgcn_s_barrier();

    for (int t = 0; t < NTk; ++t) {
        const int bi = t & 1;
        const char* Lb = (const char*)&Ls[bi][0][0];
        bf16x8 af[8], bv0, bv1, bv2, bv3;

        // ---- q0: A_k0 + B_k0 j01
#pragma unroll
        for (int i = 0; i < 8; ++i)
            af[i] = *(const bf16x8*)(Lb + 0 * 16384 + aoff + i * 1024);
        bv0 = *(const bf16x8*)(Lb + 2 * 16384 + boff);
        bv1 = *(const bf16x8*)(Lb + 2 * 16384 + boff + 1024);
        if (t + 1 < NTk) STG((t + 1) & 1, 1, pA0, pA1, (t + 1) * 64 + 32);
        __builtin_amdgcn_s_barrier();
        __builtin_amdgcn_s_setprio(1);
#pragma unroll
        for (int i = 0; i < 8; ++i) {
            acc[i][0] = __builtin_amdgcn_mfma_f32_16x16x32_bf16(af[i], bv0, acc[i][0], 0, 0, 0);
            acc[i][1] = __builtin_amdgcn_mfma_f32_16x16x32_bf16(af[i], bv1, acc[i][1], 0, 0, 0);
        }
        __builtin_amdgcn_s_setprio(0);
        __builtin_amdgcn_s_barrier();

        // ---- q1: B_k0 j23 (af reused)
        bv2 = *(const bf16x8*)(Lb + 2 * 16384 + boff + 2048);
        bv3 = *(const bf16x8*)(Lb + 2 * 16384 + boff + 3072);
        if (t + 1 < NTk) STG((t + 1) & 1, 3, pB0, pB1, (t + 1) * 64 + 32);
        if (t < NTk - 1) asm volatile("s_waitcnt vmcnt(8)" ::: "memory");
        else             asm volatile("s_waitcnt vmcnt(0)" ::: "memory");
        __builtin_amdgcn_s_barrier();
        __builtin_amdgcn_s_setprio(1);
#pragma unroll
        for (int i = 0; i < 8; ++i) {
            acc[i][2] = __builtin_amdgcn_mfma_f32_16x16x32_bf16(af[i], bv2, acc[i][2], 0, 0, 0);
            acc[i][3] = __builtin_amdgcn_mfma_f32_16x16x32_bf16(af[i], bv3, acc[i][3], 0, 0, 0);
        }
        __builtin_amdgcn_s_setprio(0);
        __builtin_amdgcn_s_barrier();

        // ---- q2: A_k1 + B_k1 j01
#pragma unroll
        for (int i = 0; i < 8; ++i)
            af[i] = *(const bf16x8*)(Lb + 1 * 16384 + aoff + i * 1024);
        bv0 = *(const bf16x8*)(Lb + 3 * 16384 + boff);
        bv1 = *(const bf16x8*)(Lb + 3 * 16384 + boff + 1024);
        if (t + 2 < NTk) STG(bi, 0, pA0, pA1, (t + 2) * 64);
        __builtin_amdgcn_s_barrier();
        __builtin_amdgcn_s_setprio(1);
#pragma unroll
        for (int i = 0; i < 8; ++i) {
            acc[i][0] = __builtin_amdgcn_mfma_f32_16x16x32_bf16(af[i], bv0, acc[i][0], 0, 0, 0);
            acc[i][1] = __builtin_amdgcn_mfma_f32_16x16x32_bf16(af[i], bv1, acc[i][1], 0, 0, 0);
        }
        __builtin_amdgcn_s_setprio(0);
        __builtin_amdgcn_s_barrier();

        // ---- q3: B_k1 j23
        bv2 = *(const bf16x8*)(Lb + 3 * 16384 + boff + 2048);
        bv3 = *(const bf16x8*)(Lb + 3 * 16384 + boff + 3072);
        if (t + 2 < NTk) STG(bi, 2, pB0, pB1, (t + 2) * 64);
        if (t < NTk - 2)       asm volatile("s_waitcnt vmcnt(8)" ::: "memory");
        else if (t == NTk - 2) asm volatile("s_waitcnt vmcnt(4)" ::: "memory");
        __builtin_amdgcn_s_barrier();
        __builtin_amdgcn_s_setprio(1);
#pragma unroll
        for (int i = 0; i < 8; ++i) {
            acc[i][2] = __builtin_amdgcn_mfma_f32_16x16x32_bf16(af[i], bv2, acc[i][2], 0, 0, 0);
            acc[i][3] = __builtin_amdgcn_mfma_f32_16x16x32_bf16(af[i], bv3, acc[i][3], 0, 0, 0);
        }
        __builtin_amdgcn_s_setprio(0);
        __builtin_amdgcn_s_barrier();
    }
#undef STG

    // C/D layout (verified m89/m91): col = lane&15, row = (lane>>4)*4 + reg
    const int col = l & 15;
    const int rbase = (l >> 4) * 4;
    const int gm0 = arow0 + wr * 128 + rbase;     // + i*16 + r
    const int gn0 = n0 + wc * 64 + col;           // + j*16

    if constexpr (MODE == 6) {
        float* Pb = (float*)O + pbase;
#pragma unroll
        for (int i = 0; i < 8; ++i) {
            int lr = wr * 128 + i * 16 + rbase;
#pragma unroll
            for (int j = 0; j < 4; ++j) {
                int lc = wc * 64 + j * 16 + col;
#pragma unroll
                for (int r = 0; r < 4; ++r)
                    Pb[(lr + r) * 256 + lc] = acc[i][j][r];
            }
        }
    } else if constexpr (MODE == 4) {
        if (n0 < 512) {
            // q branch: store exp, row-sum atomics
            unsigned short* Oq = (unsigned short*)O;
            float rs[8][4];
#pragma unroll
            for (int i = 0; i < 8; ++i)
#pragma unroll
                for (int r = 0; r < 4; ++r) rs[i][r] = 0.f;
#pragma unroll
            for (int i = 0; i < 8; ++i) {
                int gm = gm0 + i * 16;
#pragma unroll
                for (int j = 0; j < 4; ++j) {
                    int gn = gn0 + j * 16;
#pragma unroll
                    for (int r = 0; r < 4; ++r) {
                        float e = __expf(acc[i][j][r]);
                        rs[i][r] += e;
                        Oq[(long long)(gm + r) * 512 + gn] = f2b(e);
                    }
                }
            }
#pragma unroll
            for (int i = 0; i < 8; ++i)
#pragma unroll
                for (int r = 0; r < 4; ++r) {
                    float v = rs[i][r];
                    v += __shfl_xor(v, 1);
                    v += __shfl_xor(v, 2);
                    v += __shfl_xor(v, 4);
                    v += __shfl_xor(v, 8);
                    if ((l & 15) == 0)
                        atomicAdd(&Sq[gm0 + i * 16 + r], v);
                }
        } else if (n0 < 1024) {
            // k branch: store exp transposed, column-sum atomics
            const int b = arow0 >> 12;
            const int mq0 = (arow0 & 4095) + wr * 128 + rbase;
            float cs[4] = {0.f, 0.f, 0.f, 0.f};
#pragma unroll
            for (int i = 0; i < 8; ++i) {
                int mq = mq0 + i * 16;
#pragma unroll
                for (int j = 0; j < 4; ++j) {
                    int d = gn0 + j * 16 - 512;
                    float e0 = __expf(acc[i][j][0]);
                    float e1 = __expf(acc[i][j][1]);
                    float e2 = __expf(acc[i][j][2]);
                    float e3 = __expf(acc[i][j][3]);
                    cs[j] += e0 + e1 + e2 + e3;
                    us4 pk = { f2b(e0), f2b(e1), f2b(e2), f2b(e3) };
                    *(us4*)(O2 + ((long long)b * 512 + d) * 4096 + mq) = pk;
                }
            }
#pragma unroll
            for (int j = 0; j < 4; ++j) {
                float v = cs[j];
                v += __shfl_xor(v, 16);
                v += __shfl_xor(v, 32);
                if (l < 16)
                    atomicAdd(&Sk[b * 512 + gn0 + j * 16 - 512], v);
            }
        } else {
            // v branch: plain transposed store
            const int b = arow0 >> 12;
            const int mq0 = (arow0 & 4095) + wr * 128 + rbase;
#pragma unroll
            for (int i = 0; i < 8; ++i) {
                int mq = mq0 + i * 16;
#pragma unroll
                for (int j = 0; j < 4; ++j) {
                    int e_ = gn0 + j * 16 - 1024;
                    us4 pk = { f2b(acc[i][j][0]), f2b(acc[i][j][1]),
                               f2b(acc[i][j][2]), f2b(acc[i][j][3]) };
                    *(us4*)(O3 + ((long long)b * 512 + e_) * 4096 + mq) = pk;
                }
            }
        }
    } else if constexpr (MODE == 5) {
#pragma unroll
        for (int i = 0; i < 8; ++i) {
            int gm = gm0 + i * 16;
            float invs[4];
#pragma unroll
            for (int r = 0; r < 4; ++r) invs[r] = scale / Sn[gm + r];
#pragma unroll
            for (int j = 0; j < 4; ++j) {
                int gn = gn0 + j * 16;
#pragma unroll
                for (int r = 0; r < 4; ++r) {
                    long long idx = (long long)(gm + r) * 512 + gn;
                    ((unsigned short*)O)[idx] =
                        f2b(acc[i][j][r] * invs[r] + b2f(R[idx]));
                }
            }
        }
    } else {
#pragma unroll
        for (int i = 0; i < 8; ++i) {
            int gm = gm0 + i * 16;
#pragma unroll
            for (int j = 0; j < 4; ++j) {
                int gn = gn0 + j * 16;
#pragma unroll
                for (int r = 0; r < 4; ++r) {
                    long long idx = (long long)(gm + r) * 512 + gn;
                    float v = acc[i][j][r];
                    if constexpr (MODE == 0) {
                        ((unsigned short*)O)[idx] = f2b(v);
                    } else {
                        ((float*)O)[idx] = v + b2f(R[idx]);
                    }
                }
            }
        }
    }
}

// Sum 8 split-K partials, normalize by k-softmax denominator Sk[b*512+d],
// store bf16 ctxT[b, e, d]. P layout: [(b*32 + sk*4 + mt*2 + nt)][256][256].
__global__ __launch_bounds__(256) void ctx_reduce(const float* __restrict__ P,
                                                  const float* __restrict__ Sk,
                                                  unsigned short* __restrict__ Ct)
{
    long long f = (long long)blockIdx.x * 256 + threadIdx.x;  // 524288 total
    int b = (int)(f >> 16);
    int e = (int)(f >> 7) & 511;
    int d = ((int)f & 127) * 4;
    int mt = e >> 8, nt2 = d >> 8, lr = e & 255, lc = d & 255;
    long long base0 = (long long)(b * 32 + mt * 2 + nt2) * 65536 + lr * 256 + lc;
    float4 s = {0.f, 0.f, 0.f, 0.f};
#pragma unroll
    for (int sp = 0; sp < 8; ++sp) {
        float4 v = *(const float4*)(P + base0 + (long long)sp * 4 * 65536);
        s.x += v.x; s.y += v.y; s.z += v.z; s.w += v.w;
    }
    float4 sk = *(const float4*)(Sk + b * 512 + d);
    us4 o = { f2b(s.x / sk.x), f2b(s.y / sk.y), f2b(s.z / sk.z), f2b(s.w / sk.w) };
    *(us4*)(Ct + ((long long)b * 512 + e) * 512 + d) = o;
}

// ---------------------------------------------------------------------------
// conversions / init
// ---------------------------------------------------------------------------
__global__ __launch_bounds__(256) void f32_to_bf16_k(const float* __restrict__ in,
                                                     unsigned short* __restrict__ out)
{
    long long i = ((long long)blockIdx.x * 256 + threadIdx.x) * 4;
    float4 v = *(const float4*)(in + i);
    us4 o = { f2b(v.x), f2b(v.y), f2b(v.z), f2b(v.w) };
    *(us4*)(out + i) = o;
}

struct WPtrs { const float* in[5]; unsigned short* out[5]; };
__global__ __launch_bounds__(256) void conv_weights(WPtrs p)
{
    int which = blockIdx.y;
    long long i = ((long long)blockIdx.x * 256 + threadIdx.x) * 4;
    float4 v = *(const float4*)(p.in[which] + i);
    us4 o = { f2b(v.x), f2b(v.y), f2b(v.z), f2b(v.w) };
    *(us4*)(p.out[which] + i) = o;
}

__global__ __launch_bounds__(256) void zero_f32(float* __restrict__ p)
{
    long long i = ((long long)blockIdx.x * 256 + threadIdx.x) * 4;
    *(float4*)(p + i) = make_float4(0.f, 0.f, 0.f, 0.f);
}

// ---------------------------------------------------------------------------
extern "C" void kernel_launch(void* const* d_in, const int* in_sizes, int n_in,
                              void* d_out, int out_size, void* d_ws, size_t ws_size,
                              hipStream_t stream)
{
    (void)in_sizes; (void)n_in; (void)out_size; (void)ws_size;
    const float* x  = (const float*)d_in[0];
    const float* Wq = (const float*)d_in[1];
    const float* Wk = (const float*)d_in[2];
    const float* Wv = (const float*)d_in[3];
    const float* W1 = (const float*)d_in[4];
    const float* W2 = (const float*)d_in[5];
    float* out = (float*)d_out;

    const int Bn = 8, N = 4096, C = 512;
    const long long M  = (long long)Bn * N;   // 32768
    const long long XE = M * C;               // 16,777,216 elements

    char* ws = (char*)d_ws;
    size_t off = 0;
    auto carve = [&](size_t bytes) -> void* {
        void* p = ws + off;
        off += (bytes + 255) & ~(size_t)255;
        return p;
    };

    unsigned short* xb   = (unsigned short*)carve(XE * 2);
    unsigned short* wcat = (unsigned short*)carve((size_t)3 * C * C * 2); // [Wq;Wk;Wv]
    unsigned short* w1b  = (unsigned short*)carve((size_t)C * C * 2);
    unsigned short* w2b  = (unsigned short*)carve((size_t)C * C * 2);
    unsigned short* q    = (unsigned short*)carve(XE * 2);   // exp(q)
    unsigned short* kT   = (unsigned short*)carve(XE * 2);   // exp(k) [b,d,n]
    unsigned short* vT   = (unsigned short*)carve(XE * 2);   // [b,e,n]
    unsigned short* ctxT = (unsigned short*)carve((size_t)Bn * C * C * 2); // [b,e,d]
    float* Ssum = (float*)carve((size_t)(M + Bn * C) * 4);   // Sq[M] ++ Sk[Bn*C]
    float* Sq = Ssum;
    float* Sk = Ssum + M;
    unsigned short* xr = kT;       // alias: kT dead after ctx gemm
    unsigned short* h  = vT;       // alias: vT dead after ctx gemm
    float* P = (float*)d_out;      // split-K partials (8x8x2x2 x 256x256 f32
                                   // = 64MB = d_out): scratch until the final
                                   // gemm overwrites all of it

    // zero softmax-sum accumulators (36864 floats = 36 blocks x 256 x 4)
    zero_f32<<<dim3(36), 256, 0, stream>>>(Ssum);

    // dtype conversions
    f32_to_bf16_k<<<dim3((unsigned)(XE / 1024)), dim3(256), 0, stream>>>(x, xb);
    WPtrs wp = { { Wq, Wk, Wv, W1, W2 },
                 { wcat, wcat + C * C, wcat + 2 * C * C, w1b, w2b } };
    conv_weights<<<dim3((C * C) / 1024, 5), dim3(256), 0, stream>>>(wp);

    // fused q/k/v + exp + softmax-denominator atomics: M=32768, N=1536
    // grid = 128 m-tiles x 6 n-tiles = 768
    gemm256<4, 6, false, 512><<<dim3(768), 512, 0, stream>>>(
        xb, wcat, q, nullptr, kT, vT, Sq, Sk, nullptr, 512, 0, 0.f);

    // ctxT'[b,e,d] = sum_n vT[b,e,n] * ek[b,d,n]  (split-K=8 + reduce w/ 1/Sk)
    gemm256<6, 1, false, 4096><<<dim3(256), 512, 0, stream>>>(
        vT, kT, P, nullptr, nullptr, nullptr, nullptr, nullptr, nullptr,
        512, 0, 0.f);
    ctx_reduce<<<dim3(2048), 256, 0, stream>>>(P, Sk, ctxT);

    // xr[b,n,e] = (scale/Sq[n]) * sum_d eq[b,n,d]*ctxT[b,e,d] + x[b,n,e]
    gemm256<5, 2, true, 512><<<dim3(256), 512, 0, stream>>>(
        q, ctxT, xr, xb, nullptr, nullptr, nullptr, nullptr, Sq,
        512, (long long)C * C, 0.044194173824159216f);

    // h = xr @ W1.T
    gemm256<0, 2, false, 512><<<dim3(256), 512, 0, stream>>>(
        xr, w1b, h, nullptr, nullptr, nullptr, nullptr, nullptr, nullptr,
        512, 0, 0.f);

    // out = h @ W2.T + xr   (fp32 output)
    gemm256<3, 2, false, 512><<<dim3(256), 512, 0, stream>>>(
        h, w2b, out, xr, nullptr, nullptr, nullptr, nullptr, nullptr,
        512, 0, 0.f);
}

// Round 3
// 303.215 us; speedup vs baseline: 1.0556x; 1.0556x over previous
//
#include <hip/hip_runtime.h>

typedef unsigned int uint;
typedef __bf16 bf16_t;
typedef bf16_t bf16x8 __attribute__((ext_vector_type(8)));
typedef float floatx4 __attribute__((ext_vector_type(4)));

struct __align__(8) us4 { unsigned short x, y, z, w; };

__device__ __forceinline__ unsigned short f2b(float f) {
    unsigned u = __float_as_uint(f);
    u = u + 0x7FFFu + ((u >> 16) & 1u);   // RNE
    return (unsigned short)(u >> 16);
}
__device__ __forceinline__ float b2f(unsigned short h) {
    return __uint_as_float(((unsigned)h) << 16);
}

// async global->LDS, 16B per lane; LDS dest is wave-uniform base + lane*16
__device__ __forceinline__ void g2l16(const void* g, void* l) {
    __builtin_amdgcn_global_load_lds((__attribute__((address_space(1))) void*)g,
                                     (__attribute__((address_space(3))) void*)l,
                                     16, 0, 0);
}

// ---------------------------------------------------------------------------
// gemm128: O[m,n] = sum_k A[m,k]*B[n,k], K=512 fixed (16 K-tiles of BK=32).
// 128x256 tile, 512 threads = 8 waves (2M x 4N), wave-tile 64x64, acc[4][4].
//
// Occupancy-first design (R3): 3-deep LDS ring x 24KB = 72KB -> 2 blocks/CU.
// Two co-resident independent blocks interleave read/stage/MFMA phases; no
// intra-block phase engineering needed (R1/R2 showed lockstep at 1 block/CU
// pins MfmaUtil at ~24% regardless of barrier structure).
//
// Per K-tile t: { stage tile t+2 into buf (t+2)%3 (3 x g2l16/thread);
//   ds_read 8 x b128 frags; setprio(1); 16 MFMA; setprio(0);
//   vmcnt(3) (counted: t+2's 3 loads stay in flight); s_barrier }.
// Race-safety: stage at tile t targets tile t-1's buffer; tile t-1's reads
// are consumed by its MFMAs BEFORE the end-of-(t-1) barrier, which precedes
// the stage in every wave's program order. vmcnt(3)+barrier publishes tile
// t+1's loads to all waves. Tail: t=14 waits vmcnt(0) (3 loads), t=15 none.
//
// LDS buffer: rows 0..127 = A rows, 128..383 = B rows; 64B/row (32 k-elems),
// 16B-chunk swizzle chunk' = chunk ^ ((row>>1)&3) -> 2-way banks (free).
// Stage keeps linear LDS dest (g2l16); SOURCE address pre-swizzled with the
// same involution; ds_read applies the XOR (both-sides rule).
//
// Grid (MODE != 6): 1-D, XCD swizzle id&7, g=id>>3, nt=g%NTN, ms=(g/NTN)*8+xcd.
// BMS: ms decodes (batch = ms&7, mtile = ms>>3) -> batch pinned to XCD.
// MODE 0: bf16 store
// MODE 3: f32 store of acc + R (residual)
// MODE 5: bf16 store of acc*(scale/Sn[row]) + R   (attn: fused q-softmax)
// MODE 4: fused qkv, B=concat(Wq,Wk,Wv)[1536x512]:
//   n0<512    : store exp(acc) -> O (=eq), atomicAdd row sums into Sq[m]
//   512..1023 : store exp(acc) transposed -> O2 (=ekT[b,d,n]), atomicAdd
//               column sums into Sk[b*512+d]
//   >=1024    : store acc transposed -> O3 (=vT[b,e,n])
// MODE 6: ctx split-K partial. grid 512: xcd=id&7, g=id>>3; t8=g&7 ->
//   mt=t8>>1 (0..3), ntc=t8&1; slice=(g>>3)*8+xcd = b*8+sk (XCD-pinned).
//   A=vT[b, mt*128.., sk*512..], B=kT[b, ntc*256.., sk*512..], f32 store of
//   the 128x256 partial into P[slice*262144 + (mt*128+r)*512 + ntc*256 + c].
// ---------------------------------------------------------------------------
template <int MODE, int NTN, bool BMS, int LD>
__global__ __launch_bounds__(512, 4) void gemm128(
    const unsigned short* __restrict__ A, const unsigned short* __restrict__ B,
    void* __restrict__ O, const unsigned short* __restrict__ R,
    unsigned short* __restrict__ O2, unsigned short* __restrict__ O3,
    float* __restrict__ Sq, float* __restrict__ Sk,
    const float* __restrict__ Sn,
    long long sB, float scale)
{
    __shared__ __attribute__((aligned(16))) unsigned short Ls[3][12288]; // 72 KB

    const uint id = blockIdx.x;
    const int tid = threadIdx.x;
    const int l = tid & 63;
    const int w = tid >> 6;
    const int wm = (w >> 2) * 64;     // 0/64   : M-half of the 128-row tile
    const int wnb = (w & 3) * 64;     // 0..192 : N-strip of the 256-col tile

    int arow0 = 0, n0 = 0, bb = 0;
    const unsigned short* Ab;
    const unsigned short* Bbp;
    long long pbase = 0;

    if constexpr (MODE == 6) {
        const uint xcd = id & 7;
        const uint g = id >> 3;
        const int t8 = (int)(g & 7);
        const int mt = t8 >> 1, ntc = t8 & 1;
        const int slice = (int)(g >> 3) * 8 + (int)xcd;   // = b*8 + sk
        const int b6 = slice >> 3, sk6 = slice & 7;
        Ab  = A + ((long long)b6 * 512 + mt  * 128) * 4096 + sk6 * 512;
        Bbp = B + ((long long)b6 * 512 + ntc * 256) * 4096 + sk6 * 512;
        pbase = (long long)slice * 262144 + (long long)mt * 128 * 512 + ntc * 256;
    } else {
        const uint xcd = id & 7;
        const uint g = id >> 3;
        const uint nt = g % NTN;
        const uint mg = g / NTN;
        const uint ms = mg * 8 + xcd;
        if constexpr (BMS) { bb = (int)(ms & 7); arow0 = bb * 4096 + (int)(ms >> 3) * 128; }
        else               { bb = 0;             arow0 = (int)ms * 128; }
        n0 = (int)nt * 256;
        Ab  = A + (long long)arow0 * LD;
        Bbp = B + (long long)bb * sB + (long long)n0 * LD;
    }

    // ---- staging sources (pre-swizzled): thread owns LDS 16B chunks
    // {tid, tid+512, tid+1024}; chunk p (row p>>2, slot p&3) holds source
    // chunk (p&3) ^ ((row>>1)&3). Rows 0..127 = A, 128..383 = B (row-128).
    const int q_ = tid >> 2;                         // 0..127
    const int lc = (tid & 3) ^ ((tid >> 3) & 3);
    const unsigned short* pA  = Ab  + (long long)q_ * LD + lc * 8;
    const unsigned short* pB1 = Bbp + (long long)q_ * LD + lc * 8;
    const unsigned short* pB2 = Bbp + (long long)(128 + q_) * LD + lc * 8;

#define STG(bi, koff) do {                                                  \
        unsigned short* d_ = &Ls[bi][0] + tid * 8;                          \
        g2l16(pA  + (koff), d_);                                            \
        g2l16(pB1 + (koff), d_ + 4096);                                     \
        g2l16(pB2 + (koff), d_ + 8192);                                     \
    } while (0)

    // ---- ds_read fragment addressing (byte offsets within a buffer)
    const int fr = l & 15;
    const int c0 = l >> 4;
    const int swz = (c0 ^ ((fr >> 1) & 3)) << 4;
    const int aoff = (wm + fr) * 64 + swz;            // + i*1024 (i<4)
    const int boff = (128 + wnb + fr) * 64 + swz;     // + j*1024 (j<4)

    floatx4 acc[4][4] = {};

    // prologue: tiles 0,1 staged; wait tile 0 (6 issued, keep 3 in flight)
    STG(0, 0);
    STG(1, 32);
    asm volatile("s_waitcnt vmcnt(3)" ::: "memory");
    __builtin_amdgcn_s_barrier();

    int cur = 0, stb = 2;
    for (int t = 0; t < 16; ++t) {
        if (t + 2 < 16) STG(stb, (t + 2) * 32);

        const char* Lb = (const char*)&Ls[cur][0];
        bf16x8 af[4], bv[4];
#pragma unroll
        for (int i = 0; i < 4; ++i) af[i] = *(const bf16x8*)(Lb + aoff + i * 1024);
#pragma unroll
        for (int j = 0; j < 4; ++j) bv[j] = *(const bf16x8*)(Lb + boff + j * 1024);

        __builtin_amdgcn_s_setprio(1);
#pragma unroll
        for (int i = 0; i < 4; ++i)
#pragma unroll
            for (int j = 0; j < 4; ++j)
                acc[i][j] = __builtin_amdgcn_mfma_f32_16x16x32_bf16(
                    af[i], bv[j], acc[i][j], 0, 0, 0);
        __builtin_amdgcn_s_setprio(0);

        if (t < 15) {
            if (t < 14) asm volatile("s_waitcnt vmcnt(3)" ::: "memory");
            else        asm volatile("s_waitcnt vmcnt(0)" ::: "memory");
            __builtin_amdgcn_s_barrier();
        }
        cur = (cur == 2) ? 0 : cur + 1;
        stb = (stb == 2) ? 0 : stb + 1;
    }
#undef STG

    // C/D layout (verified m89/m91): col = lane&15, row = (lane>>4)*4 + reg
    const int col = l & 15;
    const int rbase = (l >> 4) * 4;
    const int gm0 = arow0 + wm + rbase;           // + i*16 + r
    const int gn0 = n0 + wnb + col;               // + j*16

    if constexpr (MODE == 6) {
        float* Pb = (float*)O + pbase;
#pragma unroll
        for (int i = 0; i < 4; ++i) {
            int lr = wm + i * 16 + rbase;
#pragma unroll
            for (int j = 0; j < 4; ++j) {
                int lcc = wnb + j * 16 + col;
#pragma unroll
                for (int r = 0; r < 4; ++r)
                    Pb[(long long)(lr + r) * 512 + lcc] = acc[i][j][r];
            }
        }
    } else if constexpr (MODE == 4) {
        if (n0 < 512) {
            // q branch: store exp, row-sum atomics
            unsigned short* Oq = (unsigned short*)O;
            float rs[4][4];
#pragma unroll
            for (int i = 0; i < 4; ++i)
#pragma unroll
                for (int r = 0; r < 4; ++r) rs[i][r] = 0.f;
#pragma unroll
            for (int i = 0; i < 4; ++i) {
                int gm = gm0 + i * 16;
#pragma unroll
                for (int j = 0; j < 4; ++j) {
                    int gn = gn0 + j * 16;
#pragma unroll
                    for (int r = 0; r < 4; ++r) {
                        float e = __expf(acc[i][j][r]);
                        rs[i][r] += e;
                        Oq[(long long)(gm + r) * 512 + gn] = f2b(e);
                    }
                }
            }
#pragma unroll
            for (int i = 0; i < 4; ++i)
#pragma unroll
                for (int r = 0; r < 4; ++r) {
                    float v = rs[i][r];
                    v += __shfl_xor(v, 1);
                    v += __shfl_xor(v, 2);
                    v += __shfl_xor(v, 4);
                    v += __shfl_xor(v, 8);
                    if ((l & 15) == 0)
                        atomicAdd(&Sq[gm0 + i * 16 + r], v);
                }
        } else if (n0 < 1024) {
            // k branch: store exp transposed, column-sum atomics
            const int b = arow0 >> 12;
            const int mq0 = (arow0 & 4095) + wm + rbase;
            float cs[4] = {0.f, 0.f, 0.f, 0.f};
#pragma unroll
            for (int i = 0; i < 4; ++i) {
                int mq = mq0 + i * 16;
#pragma unroll
                for (int j = 0; j < 4; ++j) {
                    int d = gn0 + j * 16 - 512;
                    float e0 = __expf(acc[i][j][0]);
                    float e1 = __expf(acc[i][j][1]);
                    float e2 = __expf(acc[i][j][2]);
                    float e3 = __expf(acc[i][j][3]);
                    cs[j] += e0 + e1 + e2 + e3;
                    us4 pk = { f2b(e0), f2b(e1), f2b(e2), f2b(e3) };
                    *(us4*)(O2 + ((long long)b * 512 + d) * 4096 + mq) = pk;
                }
            }
#pragma unroll
            for (int j = 0; j < 4; ++j) {
                float v = cs[j];
                v += __shfl_xor(v, 16);
                v += __shfl_xor(v, 32);
                if (l < 16)
                    atomicAdd(&Sk[b * 512 + gn0 + j * 16 - 512], v);
            }
        } else {
            // v branch: plain transposed store
            const int b = arow0 >> 12;
            const int mq0 = (arow0 & 4095) + wm + rbase;
#pragma unroll
            for (int i = 0; i < 4; ++i) {
                int mq = mq0 + i * 16;
#pragma unroll
                for (int j = 0; j < 4; ++j) {
                    int e_ = gn0 + j * 16 - 1024;
                    us4 pk = { f2b(acc[i][j][0]), f2b(acc[i][j][1]),
                               f2b(acc[i][j][2]), f2b(acc[i][j][3]) };
                    *(us4*)(O3 + ((long long)b * 512 + e_) * 4096 + mq) = pk;
                }
            }
        }
    } else if constexpr (MODE == 5) {
#pragma unroll
        for (int i = 0; i < 4; ++i) {
            int gm = gm0 + i * 16;
            float invs[4];
#pragma unroll
            for (int r = 0; r < 4; ++r) invs[r] = scale / Sn[gm + r];
#pragma unroll
            for (int j = 0; j < 4; ++j) {
                int gn = gn0 + j * 16;
#pragma unroll
                for (int r = 0; r < 4; ++r) {
                    long long idx = (long long)(gm + r) * 512 + gn;
                    ((unsigned short*)O)[idx] =
                        f2b(acc[i][j][r] * invs[r] + b2f(R[idx]));
                }
            }
        }
    } else {
#pragma unroll
        for (int i = 0; i < 4; ++i) {
            int gm = gm0 + i * 16;
#pragma unroll
            for (int j = 0; j < 4; ++j) {
                int gn = gn0 + j * 16;
#pragma unroll
                for (int r = 0; r < 4; ++r) {
                    long long idx = (long long)(gm + r) * 512 + gn;
                    float v = acc[i][j][r];
                    if constexpr (MODE == 0) {
                        ((unsigned short*)O)[idx] = f2b(v);
                    } else {
                        ((float*)O)[idx] = v + b2f(R[idx]);
                    }
                }
            }
        }
    }
}

// Sum 8 split-K partials, normalize by k-softmax denominator Sk[b*512+d],
// store bf16 ctxT[b, e, d]. P layout: [slice = b*8+sk][512 e][512 d] f32.
__global__ __launch_bounds__(256) void ctx_reduce(const float* __restrict__ P,
                                                  const float* __restrict__ Sk,
                                                  unsigned short* __restrict__ Ct)
{
    long long f = (long long)blockIdx.x * 256 + threadIdx.x;  // 524288 total
    long long base = f * 4;
    int b = (int)(base >> 18);
    int rem = (int)(base & 262143);          // e*512 + d
    int d = rem & 511;
    float4 s = {0.f, 0.f, 0.f, 0.f};
#pragma unroll
    for (int sp = 0; sp < 8; ++sp) {
        float4 v = *(const float4*)(P + (long long)(b * 8 + sp) * 262144 + rem);
        s.x += v.x; s.y += v.y; s.z += v.z; s.w += v.w;
    }
    float4 sk = *(const float4*)(Sk + b * 512 + d);
    us4 o = { f2b(s.x / sk.x), f2b(s.y / sk.y), f2b(s.z / sk.z), f2b(s.w / sk.w) };
    *(us4*)(Ct + (long long)b * 262144 + rem) = o;
}

// ---------------------------------------------------------------------------
// conversions / init
// ---------------------------------------------------------------------------
__global__ __launch_bounds__(256) void f32_to_bf16_k(const float* __restrict__ in,
                                                     unsigned short* __restrict__ out)
{
    long long i = ((long long)blockIdx.x * 256 + threadIdx.x) * 4;
    float4 v = *(const float4*)(in + i);
    us4 o = { f2b(v.x), f2b(v.y), f2b(v.z), f2b(v.w) };
    *(us4*)(out + i) = o;
}

struct WPtrs { const float* in[5]; unsigned short* out[5]; };
__global__ __launch_bounds__(256) void conv_weights(WPtrs p)
{
    int which = blockIdx.y;
    long long i = ((long long)blockIdx.x * 256 + threadIdx.x) * 4;
    float4 v = *(const float4*)(p.in[which] + i);
    us4 o = { f2b(v.x), f2b(v.y), f2b(v.z), f2b(v.w) };
    *(us4*)(p.out[which] + i) = o;
}

__global__ __launch_bounds__(256) void zero_f32(float* __restrict__ p)
{
    long long i = ((long long)blockIdx.x * 256 + threadIdx.x) * 4;
    *(float4*)(p + i) = make_float4(0.f, 0.f, 0.f, 0.f);
}

// ---------------------------------------------------------------------------
extern "C" void kernel_launch(void* const* d_in, const int* in_sizes, int n_in,
                              void* d_out, int out_size, void* d_ws, size_t ws_size,
                              hipStream_t stream)
{
    (void)in_sizes; (void)n_in; (void)out_size; (void)ws_size;
    const float* x  = (const float*)d_in[0];
    const float* Wq = (const float*)d_in[1];
    const float* Wk = (const float*)d_in[2];
    const float* Wv = (const float*)d_in[3];
    const float* W1 = (const float*)d_in[4];
    const float* W2 = (const float*)d_in[5];
    float* out = (float*)d_out;

    const int Bn = 8, N = 4096, C = 512;
    const long long M  = (long long)Bn * N;   // 32768
    const long long XE = M * C;               // 16,777,216 elements

    char* ws = (char*)d_ws;
    size_t off = 0;
    auto carve = [&](size_t bytes) -> void* {
        void* p = ws + off;
        off += (bytes + 255) & ~(size_t)255;
        return p;
    };

    unsigned short* xb   = (unsigned short*)carve(XE * 2);
    unsigned short* wcat = (unsigned short*)carve((size_t)3 * C * C * 2); // [Wq;Wk;Wv]
    unsigned short* w1b  = (unsigned short*)carve((size_t)C * C * 2);
    unsigned short* w2b  = (unsigned short*)carve((size_t)C * C * 2);
    unsigned short* q    = (unsigned short*)carve(XE * 2);   // exp(q)
    unsigned short* kT   = (unsigned short*)carve(XE * 2);   // exp(k) [b,d,n]
    unsigned short* vT   = (unsigned short*)carve(XE * 2);   // [b,e,n]
    unsigned short* ctxT = (unsigned short*)carve((size_t)Bn * C * C * 2); // [b,e,d]
    float* Ssum = (float*)carve((size_t)(M + Bn * C) * 4);   // Sq[M] ++ Sk[Bn*C]
    float* Sq = Ssum;
    float* Sk = Ssum + M;
    unsigned short* xr = kT;       // alias: kT dead after ctx gemm
    unsigned short* h  = vT;       // alias: vT dead after ctx gemm
    float* P = (float*)d_out;      // split-K partials (64 slices x 1MB = 64MB
                                   // = d_out): scratch until the final gemm
                                   // overwrites all of it

    // zero softmax-sum accumulators (36864 floats = 36 blocks x 256 x 4)
    zero_f32<<<dim3(36), 256, 0, stream>>>(Ssum);

    // dtype conversions
    f32_to_bf16_k<<<dim3((unsigned)(XE / 1024)), dim3(256), 0, stream>>>(x, xb);
    WPtrs wp = { { Wq, Wk, Wv, W1, W2 },
                 { wcat, wcat + C * C, wcat + 2 * C * C, w1b, w2b } };
    conv_weights<<<dim3((C * C) / 1024, 5), dim3(256), 0, stream>>>(wp);

    // fused q/k/v + exp + softmax-denominator atomics: M=32768, N=1536
    // grid = 256 m-tiles x 6 n-tiles = 1536 (2 blocks/CU co-resident)
    gemm128<4, 6, false, 512><<<dim3(1536), 512, 0, stream>>>(
        xb, wcat, q, nullptr, kT, vT, Sq, Sk, nullptr, 0, 0.f);

    // ctxT'[b,e,d] = sum_n vT[b,e,n] * ek[b,d,n]  (split-K=8 + reduce w/ 1/Sk)
    gemm128<6, 1, false, 4096><<<dim3(512), 512, 0, stream>>>(
        vT, kT, P, nullptr, nullptr, nullptr, nullptr, nullptr, nullptr,
        0, 0.f);
    ctx_reduce<<<dim3(2048), 256, 0, stream>>>(P, Sk, ctxT);

    // xr[b,n,e] = (scale/Sq[n]) * sum_d eq[b,n,d]*ctxT[b,e,d] + x[b,n,e]
    gemm128<5, 2, true, 512><<<dim3(512), 512, 0, stream>>>(
        q, ctxT, xr, xb, nullptr, nullptr, nullptr, nullptr, Sq,
        (long long)C * C, 0.044194173824159216f);

    // h = xr @ W1.T
    gemm128<0, 2, false, 512><<<dim3(512), 512, 0, stream>>>(
        xr, w1b, h, nullptr, nullptr, nullptr, nullptr, nullptr, nullptr,
        0, 0.f);

    // out = h @ W2.T + xr   (fp32 output)
    gemm128<3, 2, false, 512><<<dim3(512), 512, 0, stream>>>(
        h, w2b, out, xr, nullptr, nullptr, nullptr, nullptr, nullptr,
        0, 0.f);
}